// Round 7
// baseline (551.485 us; speedup 1.0000x reference)
//
#include <hip/hip_runtime.h>
#include <hip/hip_bf16.h>

// ---------------------------------------------------------------------------
// rWindowAttention fused kernel (MI355X / gfx950) — round 2 design (resubmit;
// rounds 3-6 were GPU-broker infra failures, never executed)
//
// Shapes: B=1024, N=256 (= 4 blocks x 64), C=128, H=4, Dh=32.
// One workgroup (512 thr = 8 waves) per batch. All matmuls on
// v_mfma_f32_32x32x16_bf16. Masked-bias attention over all 256 keys.
//
// Round-2 structure (vs round 0): latency-bound fix, occupancy unchanged:
//  - k/vt double-buffered in LDS; GEMM(h+1) interleaved into attention(h)
//    (independent MFMA chains fill softmax bubbles). 5 barriers total (was 9).
//  - q never touches LDS: QK B-frags built from swapped-GEMM D regs via
//    pack + v_permlane32_swap_b32 (same lane algebra as P->PV packing).
//  - softmax max/sum as binary trees (depth ~7) instead of 128-deep chains.
//  - projection deferred to epilogue: out_h [256][128] accumulates in LDS
//    (overlaid on consumed xs region; every access is wave-private-row),
//    so yacc (64 VGPRs) is only live after S dies.
//
// MFMA 32x32x16 bf16 fragment maps (lane = tid&63, lq=lane&31, lh=lane>>5):
//   A[row][k] : row = lq, k = 8*lh + j
//   B[k][col] : col = lq, k = 8*lh + j
//   C/D       : col = lq, row = (r&3) + 8*(r>>2) + 4*lh   (r = 0..15)
// ---------------------------------------------------------------------------

typedef float  f32x16 __attribute__((ext_vector_type(16)));
typedef float  f32x4_ __attribute__((ext_vector_type(4)));
typedef __bf16 bf16x8 __attribute__((ext_vector_type(8)));
typedef __bf16 bf16x2 __attribute__((ext_vector_type(2)));
typedef unsigned int  uint32x4_ __attribute__((ext_vector_type(4)));
typedef unsigned int  uint32x2_ __attribute__((ext_vector_type(2)));

#define MFMA32(a, b, c) __builtin_amdgcn_mfma_f32_32x32x16_bf16((a), (b), (c), 0, 0, 0)

static __device__ __forceinline__ unsigned int packbf2(float a, float b) {
  bf16x2 t = { (__bf16)a, (__bf16)b };
  return __builtin_bit_cast(unsigned int, t);
}
// v_permlane32_swap_b32: new_a = [a_lo | b_lo], new_b = [a_hi | b_hi]
static __device__ __forceinline__ void plswap(unsigned int &a, unsigned int &b) {
  asm volatile("v_permlane32_swap_b32 %0, %1" : "+v"(a), "+v"(b));
}

static __device__ __forceinline__ float max16(const f32x16& v) {
  float a0 = fmaxf(v[0], v[1]),  a1 = fmaxf(v[2], v[3]);
  float a2 = fmaxf(v[4], v[5]),  a3 = fmaxf(v[6], v[7]);
  float a4 = fmaxf(v[8], v[9]),  a5 = fmaxf(v[10], v[11]);
  float a6 = fmaxf(v[12], v[13]), a7 = fmaxf(v[14], v[15]);
  float b0 = fmaxf(a0, a1), b1 = fmaxf(a2, a3), b2 = fmaxf(a4, a5), b3 = fmaxf(a6, a7);
  return fmaxf(fmaxf(b0, b1), fmaxf(b2, b3));
}
static __device__ __forceinline__ float sum16(const f32x16& v) {
  float a0 = v[0] + v[1],  a1 = v[2] + v[3],  a2 = v[4] + v[5],  a3 = v[6] + v[7];
  float a4 = v[8] + v[9],  a5 = v[10] + v[11], a6 = v[12] + v[13], a7 = v[14] + v[15];
  float b0 = a0 + a1, b1 = a2 + a3, b2 = a4 + a5, b3 = a6 + a7;
  return (b0 + b1) + (b2 + b3);
}

// LDS byte offsets (total 128 KiB)
#define K0_OFF 0        // k   bf16 [256][32], 64B rows, swizzle ((n>>1)&3)<<4
#define V0_OFF 16384    // v^T bf16 [32][256], 512B rows, swizzle (d&7)<<4
#define K1_OFF 32768
#define V1_OFF 49152
#define XS_OFF 65536    // x bf16 [256][128] (staging) -> reused as out_h [256][128]

static __device__ __forceinline__ int swzA(int row, int off) {  // 64B rows
  return (row << 6) + (off ^ (((row >> 1) & 3) << 4));
}
static __device__ __forceinline__ int swzX(int row, int off) {  // 256B rows
  return (row << 8) + (off ^ ((row & 7) << 4));
}
static __device__ __forceinline__ int swzV(int row, int off) {  // 512B rows
  return (row << 9) + (off ^ ((row & 7) << 4));
}

__global__ void prep_kernel(const float* __restrict__ qw, const float* __restrict__ kvw,
                            const float* __restrict__ pw, const float* __restrict__ rpb,
                            const int* __restrict__ relidx,
                            float* __restrict__ biasT, unsigned short* __restrict__ qwt,
                            unsigned short* __restrict__ kwt, unsigned short* __restrict__ vwt,
                            unsigned short* __restrict__ pwt) {
  int gid = blockIdx.x * 256 + threadIdx.x;
  if (gid < 262144) {
    // biasT[i][h][ql][key], f32, masked block -> -1e30
    int key = gid & 255;
    int ql  = (gid >> 8) & 63;
    int h   = (gid >> 14) & 3;
    int i   = gid >> 16;
    float v;
    if ((key >> 6) == i) v = -1.0e30f;
    else                 v = rpb[relidx[(i * 64 + ql) * 256 + key] * 4 + h];
    biasT[gid] = v;
  } else {
    int wid = gid - 262144;
    if (wid < 16384) {  // transposed bf16 weights [cout][cin]
      int cin = wid & 127, cout = wid >> 7;
      qwt[wid] = __builtin_bit_cast(unsigned short, (__bf16)(qw[cin * 128 + cout] * 0.17677669529663687f));
      kwt[wid] = __builtin_bit_cast(unsigned short, (__bf16)(kvw[cin * 256 + cout]));
      vwt[wid] = __builtin_bit_cast(unsigned short, (__bf16)(kvw[cin * 256 + 128 + cout]));
      pwt[wid] = __builtin_bit_cast(unsigned short, (__bf16)(pw[cin * 128 + cout]));
    }
  }
}

__global__ __launch_bounds__(512, 2) void fused_attn(
    const float* __restrict__ x, const float* __restrict__ biasT,
    const unsigned short* __restrict__ qwt, const unsigned short* __restrict__ kwt,
    const unsigned short* __restrict__ vwt, const unsigned short* __restrict__ pwt,
    const float* __restrict__ proj_b, float* __restrict__ out) {
  __shared__ __align__(16) char smem[131072];
  const int tid  = threadIdx.x;
  const int w    = tid >> 6;    // wave id: owns q rows [32w, 32w+32)
  const int lane = tid & 63;
  const int lq   = lane & 31;
  const int lh   = lane >> 5;
  const int b    = blockIdx.x;

  // ---- stage x -> xs bf16 (coalesced float4 loads, 8B LDS writes) ----
  const float* xb = x + (size_t)b * (256 * 128);
  #pragma unroll
  for (int it = 0; it < 16; ++it) {
    int idx = it * 512 + tid;              // float4 index; row n = idx>>5, col4 = idx&31
    f32x4_ v = ((const f32x4_*)xb)[idx];
    int n = idx >> 5, c4 = idx & 31;
    uint32x2_ wv = { packbf2(v[0], v[1]), packbf2(v[2], v[3]) };
    *(uint32x2_*)(smem + XS_OFF + swzX(n, c4 * 8)) = wv;
  }
  __syncthreads();   // B1: xs visible

  // ---- wave's x-tile -> registers (32 VGPRs); xs region later becomes oh ----
  bf16x8 xf[8];
  #pragma unroll
  for (int ks = 0; ks < 8; ++ks)
    xf[ks] = *(const bf16x8*)(smem + XS_OFF + swzX(w * 32 + lq, ks * 32 + lh * 16));

  // ---- GEMM(0): q,k (swapped), v (normal) for head 0 ----
  bf16x8 qb0, qb1;                         // current head's QK B-frags (regs)
  {
    f32x16 gq, gk, gv;
    #pragma unroll
    for (int r = 0; r < 16; ++r) { gq[r] = 0.0f; gk[r] = 0.0f; gv[r] = 0.0f; }
    #pragma unroll
    for (int ks = 0; ks < 8; ++ks) {
      bf16x8 wq = *(const bf16x8*)(qwt + lq * 128 + ks * 16 + lh * 8);
      bf16x8 wk = *(const bf16x8*)(kwt + lq * 128 + ks * 16 + lh * 8);
      bf16x8 wv = *(const bf16x8*)(vwt + lq * 128 + ks * 16 + lh * 8);
      gq = MFMA32(wq, xf[ks], gq);   // D row=d, col=n
      gk = MFMA32(wk, xf[ks], gk);
      gv = MFMA32(xf[ks], wv, gv);   // D row=n, col=d
    }
    // q D-regs -> B-frags in registers (pack + permlane32_swap)
    unsigned int u0 = packbf2(gq[0], gq[1]),  u2 = packbf2(gq[4], gq[5]);
    unsigned int u1 = packbf2(gq[2], gq[3]),  u3 = packbf2(gq[6], gq[7]);
    plswap(u0, u2); plswap(u1, u3);
    uint32x4_ f0 = { u0, u1, u2, u3 };
    qb0 = __builtin_bit_cast(bf16x8, f0);
    unsigned int v0 = packbf2(gq[8], gq[9]),   v2 = packbf2(gq[12], gq[13]);
    unsigned int v1 = packbf2(gq[10], gq[11]), v3 = packbf2(gq[14], gq[15]);
    plswap(v0, v2); plswap(v1, v3);
    uint32x4_ f1 = { v0, v1, v2, v3 };
    qb1 = __builtin_bit_cast(bf16x8, f1);
    // k, vt -> LDS buf0
    #pragma unroll
    for (int g = 0; g < 4; ++g) {
      uint32x2_ k2 = { packbf2(gk[4*g+0], gk[4*g+1]), packbf2(gk[4*g+2], gk[4*g+3]) };
      *(uint32x2_*)(smem + K0_OFF + swzA(w * 32 + lq, g * 16 + lh * 8)) = k2;
      uint32x2_ v2_ = { packbf2(gv[4*g+0], gv[4*g+1]), packbf2(gv[4*g+2], gv[4*g+3]) };
      *(uint32x2_*)(smem + V0_OFF + swzV(lq, w * 64 + g * 16 + lh * 8)) = v2_;
    }
  }
  __syncthreads();   // B2: buf0 visible

  // ---- head loop: attention(h) on buf[h&1]  ||  GEMM(h+1) -> buf[(h+1)&1] ----
  #pragma unroll
  for (int h = 0; h < 4; ++h) {
    const int KB = (h & 1) ? K1_OFF : K0_OFF;
    const int VB = (h & 1) ? V1_OFF : V0_OFF;
    const int KN = (h & 1) ? K0_OFF : K1_OFF;
    const int VN = (h & 1) ? V0_OFF : V1_OFF;
    const float* biasW = biasT + ((((w >> 1) * 4 + h) * 64 + (w & 1) * 32 + lq) * 256);

    // QK^T (S^T layout: row=key, col=q) with bias C-init
    f32x16 S[8];
    float pm[8];
    #pragma unroll
    for (int kt = 0; kt < 8; ++kt) {
      f32x16 c;
      #pragma unroll
      for (int g = 0; g < 4; ++g) {
        f32x4_ bv = *(const f32x4_*)(biasW + kt * 32 + lh * 4 + g * 8);
        c[4*g+0] = bv[0]; c[4*g+1] = bv[1]; c[4*g+2] = bv[2]; c[4*g+3] = bv[3];
      }
      bf16x8 ka0 = *(const bf16x8*)(smem + KB + swzA(kt * 32 + lq, lh * 16));
      bf16x8 ka1 = *(const bf16x8*)(smem + KB + swzA(kt * 32 + lq, 32 + lh * 16));
      c = MFMA32(ka0, qb0, c);
      c = MFMA32(ka1, qb1, c);
      S[kt] = c;
      pm[kt] = max16(c);                    // tree, fills MFMA shadow
    }
    float m = fmaxf(fmaxf(fmaxf(pm[0], pm[1]), fmaxf(pm[2], pm[3])),
                    fmaxf(fmaxf(pm[4], pm[5]), fmaxf(pm[6], pm[7])));
    m = fmaxf(m, __shfl_xor(m, 32, 64));
    float ps[8];
    #pragma unroll
    for (int kt = 0; kt < 8; ++kt) {
      #pragma unroll
      for (int r = 0; r < 16; ++r) S[kt][r] = __expf(S[kt][r] - m);
      ps[kt] = sum16(S[kt]);                // tree
    }
    float l = ((ps[0] + ps[1]) + (ps[2] + ps[3])) + ((ps[4] + ps[5]) + (ps[6] + ps[7]));
    l += __shfl_xor(l, 32, 64);
    float linv = 1.0f / l;

    // PV (+ interleaved GEMM(h+1): independent MFMA chains fill bubbles)
    f32x16 pv, gq, gk, gv;
    #pragma unroll
    for (int r = 0; r < 16; ++r) { pv[r] = 0.0f; gq[r] = 0.0f; gk[r] = 0.0f; gv[r] = 0.0f; }
    const int wrow = (h + 1) * 32 + lq;     // next head's weight row
    #pragma unroll
    for (int kt = 0; kt < 8; ++kt) {
      unsigned int pk0 = packbf2(S[kt][0],  S[kt][1]);
      unsigned int pk1 = packbf2(S[kt][2],  S[kt][3]);
      unsigned int pk2 = packbf2(S[kt][4],  S[kt][5]);
      unsigned int pk3 = packbf2(S[kt][6],  S[kt][7]);
      unsigned int pk4 = packbf2(S[kt][8],  S[kt][9]);
      unsigned int pk5 = packbf2(S[kt][10], S[kt][11]);
      unsigned int pk6 = packbf2(S[kt][12], S[kt][13]);
      unsigned int pk7 = packbf2(S[kt][14], S[kt][15]);
      plswap(pk0, pk2); plswap(pk1, pk3);
      plswap(pk4, pk6); plswap(pk5, pk7);
      uint32x4_ f0 = { pk0, pk1, pk2, pk3 };
      uint32x4_ f1 = { pk4, pk5, pk6, pk7 };
      bf16x8 pb0 = __builtin_bit_cast(bf16x8, f0);
      bf16x8 pb1 = __builtin_bit_cast(bf16x8, f1);
      bf16x8 vl0 = *(const bf16x8*)(smem + VB + swzV(lq, kt * 64 + lh * 16));
      bf16x8 vl1 = *(const bf16x8*)(smem + VB + swzV(lq, kt * 64 + 32 + lh * 16));
      pv = MFMA32(vl0, pb0, pv);
      pv = MFMA32(vl1, pb1, pv);
      if (h < 3) {
        bf16x8 wq = *(const bf16x8*)(qwt + wrow * 128 + kt * 16 + lh * 8);
        bf16x8 wk = *(const bf16x8*)(kwt + wrow * 128 + kt * 16 + lh * 8);
        bf16x8 wv = *(const bf16x8*)(vwt + wrow * 128 + kt * 16 + lh * 8);
        gq = MFMA32(wq, xf[kt], gq);
        gk = MFMA32(wk, xf[kt], gk);
        gv = MFMA32(xf[kt], wv, gv);
      }
    }

    // out_h[n][h*32..+32] into oh (= xs region), wave-private rows
    #pragma unroll
    for (int g = 0; g < 4; ++g) {
      uint32x2_ o2 = { packbf2(pv[4*g+0] * linv, pv[4*g+1] * linv),
                       packbf2(pv[4*g+2] * linv, pv[4*g+3] * linv) };
      *(uint32x2_*)(smem + XS_OFF + swzX(w * 32 + lq, h * 64 + g * 16 + lh * 8)) = o2;
    }

    if (h < 3) {
      // next head's q B-frags
      unsigned int u0 = packbf2(gq[0], gq[1]),  u2 = packbf2(gq[4], gq[5]);
      unsigned int u1 = packbf2(gq[2], gq[3]),  u3 = packbf2(gq[6], gq[7]);
      plswap(u0, u2); plswap(u1, u3);
      uint32x4_ f0 = { u0, u1, u2, u3 };
      qb0 = __builtin_bit_cast(bf16x8, f0);
      unsigned int v0 = packbf2(gq[8], gq[9]),   v2 = packbf2(gq[12], gq[13]);
      unsigned int v1 = packbf2(gq[10], gq[11]), v3 = packbf2(gq[14], gq[15]);
      plswap(v0, v2); plswap(v1, v3);
      uint32x4_ f1 = { v0, v1, v2, v3 };
      qb1 = __builtin_bit_cast(bf16x8, f1);
      // next head's k, vt -> other buffer
      #pragma unroll
      for (int g = 0; g < 4; ++g) {
        uint32x2_ k2 = { packbf2(gk[4*g+0], gk[4*g+1]), packbf2(gk[4*g+2], gk[4*g+3]) };
        *(uint32x2_*)(smem + KN + swzA(w * 32 + lq, g * 16 + lh * 8)) = k2;
        uint32x2_ v2_ = { packbf2(gv[4*g+0], gv[4*g+1]), packbf2(gv[4*g+2], gv[4*g+3]) };
        *(uint32x2_*)(smem + VN + swzV(lq, w * 64 + g * 16 + lh * 8)) = v2_;
      }
      __syncthreads();   // B3/B4/B5: publish next buffers; protect read buffer
    }
  }

  // ---- deferred projection: yacc = out_h @ pwt (all heads), wave-private ----
  f32x16 yacc[4];
  #pragma unroll
  for (int nt = 0; nt < 4; ++nt)
    #pragma unroll
    for (int r = 0; r < 16; ++r) yacc[nt][r] = 0.0f;
  #pragma unroll
  for (int s = 0; s < 8; ++s) {
    bf16x8 as = *(const bf16x8*)(smem + XS_OFF + swzX(w * 32 + lq, s * 32 + lh * 16));
    #pragma unroll
    for (int nt = 0; nt < 4; ++nt) {
      bf16x8 pb = *(const bf16x8*)(pwt + (nt * 32 + lq) * 128 + s * 16 + lh * 8);
      yacc[nt] = MFMA32(as, pb, yacc[nt]);
    }
  }

  // ---- epilogue: + proj_b, fp32 store ----
  float* yb = out + (size_t)b * (256 * 128);
  #pragma unroll
  for (int nt = 0; nt < 4; ++nt) {
    float pbv = proj_b[nt * 32 + lq];
    #pragma unroll
    for (int g = 0; g < 4; ++g)
      #pragma unroll
      for (int r2 = 0; r2 < 4; ++r2) {
        int n = w * 32 + 8 * g + 4 * lh + r2;
        yb[n * 128 + nt * 32 + lq] = yacc[nt][4 * g + r2] + pbv;
      }
  }
}

extern "C" void kernel_launch(void* const* d_in, const int* in_sizes, int n_in,
                              void* d_out, int out_size, void* d_ws, size_t ws_size,
                              hipStream_t stream) {
  (void)in_sizes; (void)n_in; (void)out_size; (void)ws_size;
  const float* x      = (const float*)d_in[0];
  const float* qw     = (const float*)d_in[1];
  const float* kvw    = (const float*)d_in[2];
  const float* pw     = (const float*)d_in[3];
  const float* pb     = (const float*)d_in[4];
  const float* rpb    = (const float*)d_in[5];
  const int*   relidx = (const int*)d_in[6];
  float* out = (float*)d_out;

  char* ws = (char*)d_ws;              // needs ~1.18 MiB of workspace
  float* biasT          = (float*)ws;                         // 1 MiB
  unsigned short* qwt   = (unsigned short*)(ws + 1048576);    // 32 KiB each
  unsigned short* kwt   = (unsigned short*)(ws + 1048576 + 32768);
  unsigned short* vwt   = (unsigned short*)(ws + 1048576 + 65536);
  unsigned short* pwt   = (unsigned short*)(ws + 1048576 + 98304);

  prep_kernel<<<dim3(1088), dim3(256), 0, stream>>>(qw, kvw, pw, rpb, relidx,
                                                    biasT, qwt, kwt, vwt, pwt);
  fused_attn<<<dim3(1024), dim3(512), 0, stream>>>(x, biasT, qwt, kwt, vwt, pwt, pb, out);
}